// Round 15
// baseline (390.728 us; speedup 1.0000x reference)
//
#include <hip/hip_runtime.h>
#include <cstdint>

#define K_NE 16
// DIAGNOSTIC ROUND (r10 playbook): score x3, topk read+select x4 — idempotent
// reps surface both kernels above the harness's ~230us poison-fill dispatches
// so rocprof top-5 shows their counters. Opaque-zero address offsets defeat
// loop-invariant hoisting (rule #17).
#define SCORE_REP 3
#define TOPK_REP 4
constexpr int B = 8, N = 2048, F = 128;
constexpr size_t NSEND = (size_t)B * N;                 // 16384 sender rows
constexpr size_t EDGE_FLOATS = NSEND * K_NE * 256;      // 67,108,864
constexpr size_t SEND_FLOATS = (size_t)B * N * N;       // 33,554,432

typedef _Float16 half8 __attribute__((ext_vector_type(8)));
typedef _Float16 half4 __attribute__((ext_vector_type(4)));
typedef float floatx4 __attribute__((ext_vector_type(4)));

#define SCALE 2048.0f                    // exact power of 2
#define INV_SC2 2.384185791015625e-07f   // 2^-22, exact
#define F16_MIN_NORM 6.103515625e-05f    // 2^-14

// ---------------- K0: row norms (one wave per 128-float row) ----------------
__global__ __launch_bounds__(256) void norms_kernel(const float* __restrict__ X,
                                                    float* __restrict__ out) {
    int tid = blockIdx.x * 256 + threadIdx.x;
    int w = tid >> 6, lane = tid & 63;
    const float2 v = ((const float2*)(X + (size_t)w * F))[lane];
    float s = v.x * v.x + v.y * v.y;
    #pragma unroll
    for (int off = 32; off; off >>= 1) s += __shfl_xor(s, off);
    if (lane == 0) out[w] = s;
}

// ---------------- K0b: f32 -> scaled (f16 hi, f16 lo), denormal-free --------
__global__ __launch_bounds__(256) void convert_kernel(const float* __restrict__ S,
                                                      const float* __restrict__ Rv,
                                                      _Float16* __restrict__ SH,
                                                      _Float16* __restrict__ SL,
                                                      _Float16* __restrict__ RH,
                                                      _Float16* __restrict__ RL) {
    const int i = blockIdx.x * 256 + threadIdx.x;   // quad index
    const int half_n = (int)(NSEND * F / 4);        // 524288 quads per matrix
    const float* X; _Float16 *H, *L; int q;
    if (i < half_n) { X = S;  H = SH; L = SL; q = i; }
    else            { X = Rv; H = RH; L = RL; q = i - half_n; }
    const float4 v = ((const float4*)X)[q];
    float a[4] = {v.x * SCALE, v.y * SCALE, v.z * SCALE, v.w * SCALE};
    half4 h, l;
    #pragma unroll
    for (int c = 0; c < 4; ++c) {
        _Float16 hh = (_Float16)a[c];
        if (fabsf((float)hh) < F16_MIN_NORM) hh = (_Float16)0.0f;
        float lf = a[c] - (float)hh;
        _Float16 ll = (_Float16)lf;
        if (fabsf((float)ll) < F16_MIN_NORM) ll = (_Float16)0.0f;
        ((_Float16*)&h)[c] = hh;
        ((_Float16*)&l)[c] = ll;
    }
    *(half4*)(H + 4 * (size_t)q) = h;
    *(half4*)(L + 4 * (size_t)q) = l;
}

// ---------------- K1: MFMA score matrix (r13 structure, x3 reps) ------------
__global__ __launch_bounds__(256) void score_mfma_kernel(
        const _Float16* __restrict__ SH, const _Float16* __restrict__ SL,
        const _Float16* __restrict__ RH, const _Float16* __restrict__ RL,
        const float* __restrict__ x2, const float* __restrict__ y2,
        float* __restrict__ scores) {
    const int bx = blockIdx.x, by = blockIdx.y, bz = blockIdx.z;
    const int t = threadIdx.x, lane = t & 63, wv = t >> 6;
    const int row0 = by * 128 + (wv >> 1) * 64;
    const int col0 = bx * 128 + (wv & 1) * 64;
    const int lr = lane & 15, lk = (lane >> 4) * 8;

    const size_t sOff = ((size_t)(bz * N + row0 + lr)) * F + lk;
    const size_t rOff = ((size_t)(bz * N + col0 + lr)) * F + lk;

    float* outb = scores + (size_t)bz * N * N;
    const float* x2b = x2 + (size_t)bz * N;
    const float* y2b = y2 + (size_t)bz * N;

    #pragma unroll 1
    for (int rep = 0; rep < SCORE_REP; ++rep) {
        int zero = 0;
        asm volatile("" : "+v"(zero));        // opaque 0: defeats hoisting
        const _Float16* pSH = SH + sOff + zero;
        const _Float16* pSL = SL + sOff + zero;
        const _Float16* pRH = RH + rOff + zero;
        const _Float16* pRL = RL + rOff + zero;

        floatx4 acc[4][4] = {};

        #pragma unroll
        for (int ks = 0; ks < 4; ++ks) {
            const int ko = ks * 32;
            half8 ah[4], al[4];
            #pragma unroll
            for (int i = 0; i < 4; ++i) {
                ah[i] = *(const half8*)(pSH + (size_t)i * 16 * F + ko);
                al[i] = *(const half8*)(pSL + (size_t)i * 16 * F + ko);
            }
            #pragma unroll
            for (int j = 0; j < 4; ++j) {
                const half8 bh = *(const half8*)(pRH + (size_t)j * 16 * F + ko);
                const half8 bl = *(const half8*)(pRL + (size_t)j * 16 * F + ko);
                #pragma unroll
                for (int i = 0; i < 4; ++i) {
                    acc[i][j] = __builtin_amdgcn_mfma_f32_16x16x32_f16(ah[i], bh, acc[i][j], 0, 0, 0);
                    acc[i][j] = __builtin_amdgcn_mfma_f32_16x16x32_f16(ah[i], bl, acc[i][j], 0, 0, 0);
                    acc[i][j] = __builtin_amdgcn_mfma_f32_16x16x32_f16(al[i], bh, acc[i][j], 0, 0, 0);
                }
            }
        }

        #pragma unroll
        for (int j = 0; j < 4; ++j) {
            const int col = col0 + j * 16 + lr;
            const float yv = y2b[col];
            #pragma unroll
            for (int i = 0; i < 4; ++i) {
                #pragma unroll
                for (int r = 0; r < 4; ++r) {
                    const int row = row0 + i * 16 + (lane >> 4) * 4 + r;
                    const float d = acc[i][j][r] * INV_SC2;
                    outb[(size_t)row * N + col] = fabsf((-2.0f * d + x2b[row]) + yv);
                }
            }
        }
    }
}

// ------- K2: fused top-16 (threshold+bitonic, x4 reps) + conn + edges -------
__global__ __launch_bounds__(256) void topk_fused_kernel(const float* __restrict__ S,
                                                         const float* __restrict__ Rv,
                                                         float* __restrict__ scores,
                                                         float* __restrict__ edges_out) {
    __shared__ uint32_t rowbuf[4][N];     // 32 KB, lane-private slices
    __shared__ double candbuf[4][64];     // 2 KB candidate buffers
    const int t = threadIdx.x;
    const int lane = t & 63;
    const int w = t >> 6;
    const int g = blockIdx.x * 4 + w;     // global sender id 0..16383
    const int bz = g >> 11;               // batch
    uint32_t* lds = rowbuf[w];
    double* cbuf = candbuf[w];
    float* srowp = scores + (size_t)g * N;
    const double MAGIC = 4503599627370496.0;   // 2^52

    int ixs[16];
    #pragma unroll 1
    for (int rep = 0; rep < TOPK_REP; ++rep) {
        int zero = 0;
        asm volatile("" : "+v"(zero));        // opaque 0: defeats hoisting
        const uint4* sr = (const uint4*)srowp + zero;

        // ---- load row -> LDS keys; per-lane value-min --------------------
        uint32_t mk = 0xFFFFFFFFu;
        #pragma unroll
        for (int jj = 0; jj < 8; ++jj) {
            uint4 u = sr[jj * 64 + lane];
            *(uint4*)(&lds[jj * 256 + lane * 4]) = u;
            mk = mk < u.x ? mk : u.x;
            mk = mk < u.y ? mk : u.y;
            mk = mk < u.z ? mk : u.z;
            mk = mk < u.w ? mk : u.w;
        }

        // ---- bitonic sort of lane-mins -> T16 = sorted[15] ---------------
        uint32_t v = mk;
        #pragma unroll
        for (int k = 2; k <= 64; k <<= 1) {
            #pragma unroll
            for (int j = k >> 1; j >= 1; j >>= 1) {
                uint32_t o = (uint32_t)__shfl_xor((int)v, j);
                const bool take_min = (((lane & j) == 0) == ((lane & k) == 0));
                const uint32_t mn = v < o ? v : o;
                const uint32_t mx = v < o ? o : v;
                v = take_min ? mn : mx;
            }
        }
        const uint32_t T16 = (uint32_t)__shfl((int)v, 15);

        // ---- gather candidates (key <= T16), slot-ordered ----------------
        int cnt = 0;
        #pragma unroll
        for (int jj = 0; jj < 8; ++jj) {
            const uint4 u = *(const uint4*)(&lds[jj * 256 + lane * 4]);
            #pragma unroll
            for (int c = 0; c < 4; ++c) {
                const uint32_t key = (c == 0) ? u.x : (c == 1) ? u.y : (c == 2) ? u.z : u.w;
                const bool f = key <= T16;
                const unsigned long long m = __ballot(f);
                if (f) {
                    const int pos = cnt + __popcll(m & ((1ull << lane) - 1ull));
                    if (pos < 64)
                        cbuf[pos] = (double)key * 2048.0 + (double)(jj * 256 + lane * 4 + c);
                }
                cnt += __popcll(m);
            }
        }

        if (cnt <= 64) {
            double d = (lane < cnt) ? cbuf[lane] : 1e300;
            #pragma unroll
            for (int k = 2; k <= 64; k <<= 1) {
                #pragma unroll
                for (int j = k >> 1; j >= 1; j >>= 1) {
                    const double o = __shfl_xor(d, j);
                    const bool take_min = (((lane & j) == 0) == ((lane & k) == 0));
                    d = take_min ? fmin(d, o) : fmax(d, o);
                }
            }
            const int myidx = (int)(__double_as_longlong(d + MAGIC) & 2047);
            #pragma unroll
            for (int e = 0; e < 16; ++e) ixs[e] = __shfl(myidx, e);
        } else {
            // ---- fallback (tie storm): exact iterative owner-rescan ------
            uint32_t fk = 0xFFFFFFFFu, fi = 0;
            #pragma unroll
            for (int jj = 0; jj < 8; ++jj) {
                const uint4 u = *(const uint4*)(&lds[jj * 256 + lane * 4]);
                const uint32_t base = (uint32_t)(jj * 256 + lane * 4);
                if (u.x < fk) { fk = u.x; fi = base; }
                if (u.y < fk) { fk = u.y; fi = base + 1; }
                if (u.z < fk) { fk = u.z; fi = base + 2; }
                if (u.w < fk) { fk = u.w; fi = base + 3; }
            }
            #pragma unroll
            for (int it = 0; it < 16; ++it) {
                const uint32_t ck = fk, ci = fi;
                uint32_t gk = fk, gi = fi;
                #pragma unroll
                for (int off = 32; off; off >>= 1) {
                    uint32_t ok = (uint32_t)__shfl_xor((int)gk, off);
                    uint32_t oi = (uint32_t)__shfl_xor((int)gi, off);
                    if (ok < gk || (ok == gk && oi < gi)) { gk = ok; gi = oi; }
                }
                ixs[it] = (int)gi;
                if (ck == gk && ci == gi) {
                    lds[gi] = 0xFFFFFFFFu;
                    fk = 0xFFFFFFFFu; fi = 0;
                    #pragma unroll
                    for (int jj = 0; jj < 8; ++jj) {
                        const uint4 u = *(const uint4*)(&lds[jj * 256 + lane * 4]);
                        const uint32_t base = (uint32_t)(jj * 256 + lane * 4);
                        if (u.x < fk) { fk = u.x; fi = base; }
                        if (u.y < fk) { fk = u.y; fi = base + 1; }
                        if (u.z < fk) { fk = u.z; fi = base + 2; }
                        if (u.w < fk) { fk = u.w; fi = base + 3; }
                    }
                }
            }
        }
        asm volatile("" :: "v"(ixs[0]), "v"(ixs[15]));   // keep each rep live
    }

    // ---- ranks: output slot = ascending receiver-index position -----------
    int rank[16];
    #pragma unroll
    for (int e = 0; e < 16; ++e) {
        int r = 0;
        #pragma unroll
        for (int f = 0; f < 16; ++f) r += (ixs[f] < ixs[e]) ? 1 : 0;
        rank[e] = r;
    }

    // ---- connectivity row (overwrites this wave's score row) --------------
    uint32_t mask = 0;
    #pragma unroll
    for (int e = 0; e < 16; ++e) {
        const int ix = ixs[e];
        const int lane_t = (ix >> 2) & 63;
        const int bitpos = ((ix >> 8) << 2) | (ix & 3);
        if (lane == lane_t) mask |= (1u << bitpos);
    }
    #pragma unroll
    for (int j = 0; j < 8; ++j) {
        float4 vv;
        vv.x = (mask >> (j * 4 + 0)) & 1u ? 1.f : 0.f;
        vv.y = (mask >> (j * 4 + 1)) & 1u ? 1.f : 0.f;
        vv.z = (mask >> (j * 4 + 2)) & 1u ? 1.f : 0.f;
        vv.w = (mask >> (j * 4 + 3)) & 1u ? 1.f : 0.f;
        *(float4*)(srowp + j * 256 + lane * 4) = vv;
    }

    // ---- edge rows: [sender_feat(128) | recv_feat(128)] -------------------
    const float* srow = S + (size_t)g * F;
    const float* rb = Rv + (size_t)bz * N * F;
    float4 vs = {0.f, 0.f, 0.f, 0.f};
    if (lane < 32) vs = *(const float4*)(srow + lane * 4);
    #pragma unroll
    for (int e = 0; e < 16; ++e) {
        float4 vv = vs;
        if (lane >= 32)
            vv = *(const float4*)(rb + (size_t)ixs[e] * F + (lane - 32) * 4);
        *(float4*)(edges_out + ((size_t)g * K_NE + rank[e]) * 256 + lane * 4) = vv;
    }
}

extern "C" void kernel_launch(void* const* d_in, const int* in_sizes, int n_in,
                              void* d_out, int out_size, void* d_ws, size_t ws_size,
                              hipStream_t stream) {
    (void)in_sizes; (void)n_in; (void)out_size; (void)ws_size;
    const float* recv = (const float*)d_in[0];
    const float* send = (const float*)d_in[1];
    float* out = (float*)d_out;
    float* sender_mat = out + EDGE_FLOATS;       // score scratch, then conn matrix
    float* x2 = (float*)((char*)d_ws + (262144u * 4));
    float* y2 = x2 + NSEND;

    // f16 hi/lo staging lives in the edges region (dead until topk_fused).
    _Float16* SH = (_Float16*)out;
    _Float16* SL = SH + NSEND * F;
    _Float16* RH = SL + NSEND * F;
    _Float16* RL = RH + NSEND * F;               // total 16.8 MB << 256 MB

    norms_kernel<<<4096, 256, 0, stream>>>(send, x2);
    norms_kernel<<<4096, 256, 0, stream>>>(recv, y2);
    convert_kernel<<<4096, 256, 0, stream>>>(send, recv, SH, SL, RH, RL);
    dim3 g1(16, 16, 8);
    score_mfma_kernel<<<g1, 256, 0, stream>>>(SH, SL, RH, RL, x2, y2, sender_mat);
    topk_fused_kernel<<<4096, 256, 0, stream>>>(send, recv, sender_mat, out);
}

// Round 16
// 172.118 us; speedup vs baseline: 2.2701x; 2.2701x over previous
//
#include <hip/hip_runtime.h>
#include <cstdint>

#define K_NE 16
constexpr int B = 8, N = 2048, F = 128;
constexpr size_t NSEND = (size_t)B * N;                 // 16384 sender rows
constexpr size_t EDGE_FLOATS = NSEND * K_NE * 256;      // 67,108,864
constexpr size_t SEND_FLOATS = (size_t)B * N * N;       // 33,554,432

typedef _Float16 half8 __attribute__((ext_vector_type(8)));
typedef _Float16 half4 __attribute__((ext_vector_type(4)));
typedef float floatx4 __attribute__((ext_vector_type(4)));

#define SCALE 2048.0f                    // exact power of 2
#define INV_SC2 2.384185791015625e-07f   // 2^-22, exact
#define F16_MIN_NORM 6.103515625e-05f    // 2^-14

// ---------------- K0: row norms (one wave per 128-float row) ----------------
__global__ __launch_bounds__(256) void norms_kernel(const float* __restrict__ X,
                                                    float* __restrict__ out) {
    int tid = blockIdx.x * 256 + threadIdx.x;
    int w = tid >> 6, lane = tid & 63;
    const float2 v = ((const float2*)(X + (size_t)w * F))[lane];
    float s = v.x * v.x + v.y * v.y;
    #pragma unroll
    for (int off = 32; off; off >>= 1) s += __shfl_xor(s, off);
    if (lane == 0) out[w] = s;
}

// ---------------- K0b: f32 -> scaled (f16 hi, f16 lo), denormal-free --------
__global__ __launch_bounds__(256) void convert_kernel(const float* __restrict__ S,
                                                      const float* __restrict__ Rv,
                                                      _Float16* __restrict__ SH,
                                                      _Float16* __restrict__ SL,
                                                      _Float16* __restrict__ RH,
                                                      _Float16* __restrict__ RL) {
    const int i = blockIdx.x * 256 + threadIdx.x;   // quad index
    const int half_n = (int)(NSEND * F / 4);        // 524288 quads per matrix
    const float* X; _Float16 *H, *L; int q;
    if (i < half_n) { X = S;  H = SH; L = SL; q = i; }
    else            { X = Rv; H = RH; L = RL; q = i - half_n; }
    const float4 v = ((const float4*)X)[q];
    float a[4] = {v.x * SCALE, v.y * SCALE, v.z * SCALE, v.w * SCALE};
    half4 h, l;
    #pragma unroll
    for (int c = 0; c < 4; ++c) {
        _Float16 hh = (_Float16)a[c];
        if (fabsf((float)hh) < F16_MIN_NORM) hh = (_Float16)0.0f;
        float lf = a[c] - (float)hh;
        _Float16 ll = (_Float16)lf;
        if (fabsf((float)ll) < F16_MIN_NORM) ll = (_Float16)0.0f;
        ((_Float16*)&h)[c] = hh;
        ((_Float16*)&l)[c] = ll;
    }
    *(half4*)(H + 4 * (size_t)q) = h;
    *(half4*)(L + 4 * (size_t)q) = l;
}

// ---------------- K1: MFMA score matrix, LDS-staged double-buffered ---------
// 128x128 block, 4 waves (2x2 of 64x64, acc[4][4]); BK=32 chunks staged
// cooperatively into conflict-free LDS [hi/lo][kg][row][8] (f16), dbuf with
// one barrier per chunk; next chunk's global loads prefetched into registers
// before the MFMA block so L2 latency hides under 48 MFMAs. Element mapping
// and per-acc MFMA chain order are IDENTICAL to r13 -> bit-identical scores.
__global__ __launch_bounds__(256) void score_mfma_kernel(
        const _Float16* __restrict__ SH, const _Float16* __restrict__ SL,
        const _Float16* __restrict__ RH, const _Float16* __restrict__ RL,
        const float* __restrict__ x2, const float* __restrict__ y2,
        float* __restrict__ scores) {
    __shared__ __attribute__((aligned(16))) _Float16 lA[2][2][4][128][8]; // 32 KB
    __shared__ __attribute__((aligned(16))) _Float16 lB[2][2][4][128][8]; // 32 KB
    const int bx = blockIdx.x, by = blockIdx.y, bz = blockIdx.z;
    const int t = threadIdx.x, lane = t & 63, wv = t >> 6;
    const int wrow0 = (wv >> 1) * 64;
    const int wcol0 = (wv & 1) * 64;
    const int lr = lane & 15, kg = lane >> 4;

    // staging slots: s = t + i*256 (i=0..3) covers 2(h)*4(kg)*128(row);
    // kg fastest -> 4 consecutive lanes read 64B contiguous global (coalesced)
    int s_h[4], s_kg[4], s_row[4];
    #pragma unroll
    for (int i = 0; i < 4; ++i) {
        const int s = t + (i << 8);
        s_h[i]   = s >> 9;
        s_row[i] = (s & 511) >> 2;
        s_kg[i]  = s & 3;
    }
    const size_t baseA = (size_t)(bz * N + by * 128);
    const size_t baseB = (size_t)(bz * N + bx * 128);

    // prologue: chunk 0 -> buf 0
    #pragma unroll
    for (int i = 0; i < 4; ++i) {
        const _Float16* sa = (s_h[i] ? SL : SH) + (baseA + s_row[i]) * F + s_kg[i] * 8;
        const _Float16* sb = (s_h[i] ? RL : RH) + (baseB + s_row[i]) * F + s_kg[i] * 8;
        *(half8*)&lA[0][s_h[i]][s_kg[i]][s_row[i]][0] = *(const half8*)sa;
        *(half8*)&lB[0][s_h[i]][s_kg[i]][s_row[i]][0] = *(const half8*)sb;
    }
    __syncthreads();

    floatx4 acc[4][4] = {};

    #pragma unroll
    for (int kc = 0; kc < 4; ++kc) {    // 4 chunks of BK=32 (k = kc*32 + kg*8 + j)
        const int cur = kc & 1;
        half8 pa[4], pb[4];
        if (kc < 3) {                   // prefetch next chunk (in flight during MFMA)
            const int ko = (kc + 1) * 32;
            #pragma unroll
            for (int i = 0; i < 4; ++i) {
                pa[i] = *(const half8*)((s_h[i] ? SL : SH) + (baseA + s_row[i]) * F + ko + s_kg[i] * 8);
                pb[i] = *(const half8*)((s_h[i] ? RL : RH) + (baseB + s_row[i]) * F + ko + s_kg[i] * 8);
            }
        }
        half8 ah[4], al[4];
        #pragma unroll
        for (int i = 0; i < 4; ++i) {
            ah[i] = *(const half8*)&lA[cur][0][kg][wrow0 + i * 16 + lr][0];
            al[i] = *(const half8*)&lA[cur][1][kg][wrow0 + i * 16 + lr][0];
        }
        #pragma unroll
        for (int j = 0; j < 4; ++j) {
            const half8 bh = *(const half8*)&lB[cur][0][kg][wcol0 + j * 16 + lr][0];
            const half8 bl = *(const half8*)&lB[cur][1][kg][wcol0 + j * 16 + lr][0];
            #pragma unroll
            for (int i = 0; i < 4; ++i) {
                acc[i][j] = __builtin_amdgcn_mfma_f32_16x16x32_f16(ah[i], bh, acc[i][j], 0, 0, 0);
                acc[i][j] = __builtin_amdgcn_mfma_f32_16x16x32_f16(ah[i], bl, acc[i][j], 0, 0, 0);
                acc[i][j] = __builtin_amdgcn_mfma_f32_16x16x32_f16(al[i], bh, acc[i][j], 0, 0, 0);
            }
        }
        if (kc < 3) {
            const int nxt = cur ^ 1;    // write other buffer; one barrier/chunk
            #pragma unroll
            for (int i = 0; i < 4; ++i) {
                *(half8*)&lA[nxt][s_h[i]][s_kg[i]][s_row[i]][0] = pa[i];
                *(half8*)&lB[nxt][s_h[i]][s_kg[i]][s_row[i]][0] = pb[i];
            }
            __syncthreads();
        }
    }

    float* outb = scores + (size_t)bz * N * N;
    const float* x2b = x2 + (size_t)bz * N;
    const float* y2b = y2 + (size_t)bz * N;
    #pragma unroll
    for (int j = 0; j < 4; ++j) {
        const int col = bx * 128 + wcol0 + j * 16 + lr;
        const float yv = y2b[col];
        #pragma unroll
        for (int i = 0; i < 4; ++i) {
            #pragma unroll
            for (int r = 0; r < 4; ++r) {
                const int row = by * 128 + wrow0 + i * 16 + (lane >> 4) * 4 + r;
                const float d = acc[i][j][r] * INV_SC2;   // exact unscale
                outb[(size_t)row * N + col] = fabsf((-2.0f * d + x2b[row]) + yv);
            }
        }
    }
}

// ------- K2: fused top-16 via threshold filter + bitonic select (r14) -------
__global__ __launch_bounds__(256) void topk_fused_kernel(const float* __restrict__ S,
                                                         const float* __restrict__ Rv,
                                                         float* __restrict__ scores,
                                                         float* __restrict__ edges_out) {
    __shared__ uint32_t rowbuf[4][N];     // 32 KB, lane-private slices
    __shared__ double candbuf[4][64];     // 2 KB candidate buffers
    const int t = threadIdx.x;
    const int lane = t & 63;
    const int w = t >> 6;
    const int g = blockIdx.x * 4 + w;     // global sender id 0..16383
    const int bz = g >> 11;               // batch
    uint32_t* lds = rowbuf[w];
    double* cbuf = candbuf[w];
    float* srowp = scores + (size_t)g * N;
    const uint4* sr = (const uint4*)srowp;
    const double MAGIC = 4503599627370496.0;   // 2^52

    uint32_t mk = 0xFFFFFFFFu;
    #pragma unroll
    for (int jj = 0; jj < 8; ++jj) {
        uint4 u = sr[jj * 64 + lane];
        *(uint4*)(&lds[jj * 256 + lane * 4]) = u;
        mk = mk < u.x ? mk : u.x;
        mk = mk < u.y ? mk : u.y;
        mk = mk < u.z ? mk : u.z;
        mk = mk < u.w ? mk : u.w;
    }

    uint32_t v = mk;
    #pragma unroll
    for (int k = 2; k <= 64; k <<= 1) {
        #pragma unroll
        for (int j = k >> 1; j >= 1; j >>= 1) {
            uint32_t o = (uint32_t)__shfl_xor((int)v, j);
            const bool take_min = (((lane & j) == 0) == ((lane & k) == 0));
            const uint32_t mn = v < o ? v : o;
            const uint32_t mx = v < o ? o : v;
            v = take_min ? mn : mx;
        }
    }
    const uint32_t T16 = (uint32_t)__shfl((int)v, 15);

    int cnt = 0;
    #pragma unroll
    for (int jj = 0; jj < 8; ++jj) {
        const uint4 u = *(const uint4*)(&lds[jj * 256 + lane * 4]);
        #pragma unroll
        for (int c = 0; c < 4; ++c) {
            const uint32_t key = (c == 0) ? u.x : (c == 1) ? u.y : (c == 2) ? u.z : u.w;
            const bool f = key <= T16;
            const unsigned long long m = __ballot(f);
            if (f) {
                const int pos = cnt + __popcll(m & ((1ull << lane) - 1ull));
                if (pos < 64)
                    cbuf[pos] = (double)key * 2048.0 + (double)(jj * 256 + lane * 4 + c);
            }
            cnt += __popcll(m);
        }
    }

    int ixs[16];
    if (cnt <= 64) {
        double d = (lane < cnt) ? cbuf[lane] : 1e300;
        #pragma unroll
        for (int k = 2; k <= 64; k <<= 1) {
            #pragma unroll
            for (int j = k >> 1; j >= 1; j >>= 1) {
                const double o = __shfl_xor(d, j);
                const bool take_min = (((lane & j) == 0) == ((lane & k) == 0));
                d = take_min ? fmin(d, o) : fmax(d, o);
            }
        }
        const int myidx = (int)(__double_as_longlong(d + MAGIC) & 2047);
        #pragma unroll
        for (int e = 0; e < 16; ++e) ixs[e] = __shfl(myidx, e);
    } else {
        uint32_t fk = 0xFFFFFFFFu, fi = 0;
        #pragma unroll
        for (int jj = 0; jj < 8; ++jj) {
            const uint4 u = *(const uint4*)(&lds[jj * 256 + lane * 4]);
            const uint32_t base = (uint32_t)(jj * 256 + lane * 4);
            if (u.x < fk) { fk = u.x; fi = base; }
            if (u.y < fk) { fk = u.y; fi = base + 1; }
            if (u.z < fk) { fk = u.z; fi = base + 2; }
            if (u.w < fk) { fk = u.w; fi = base + 3; }
        }
        #pragma unroll
        for (int it = 0; it < 16; ++it) {
            const uint32_t ck = fk, ci = fi;
            uint32_t gk = fk, gi = fi;
            #pragma unroll
            for (int off = 32; off; off >>= 1) {
                uint32_t ok = (uint32_t)__shfl_xor((int)gk, off);
                uint32_t oi = (uint32_t)__shfl_xor((int)gi, off);
                if (ok < gk || (ok == gk && oi < gi)) { gk = ok; gi = oi; }
            }
            ixs[it] = (int)gi;
            if (ck == gk && ci == gi) {
                lds[gi] = 0xFFFFFFFFu;
                fk = 0xFFFFFFFFu; fi = 0;
                #pragma unroll
                for (int jj = 0; jj < 8; ++jj) {
                    const uint4 u = *(const uint4*)(&lds[jj * 256 + lane * 4]);
                    const uint32_t base = (uint32_t)(jj * 256 + lane * 4);
                    if (u.x < fk) { fk = u.x; fi = base; }
                    if (u.y < fk) { fk = u.y; fi = base + 1; }
                    if (u.z < fk) { fk = u.z; fi = base + 2; }
                    if (u.w < fk) { fk = u.w; fi = base + 3; }
                }
            }
        }
    }

    int rank[16];
    #pragma unroll
    for (int e = 0; e < 16; ++e) {
        int r = 0;
        #pragma unroll
        for (int f = 0; f < 16; ++f) r += (ixs[f] < ixs[e]) ? 1 : 0;
        rank[e] = r;
    }

    uint32_t mask = 0;
    #pragma unroll
    for (int e = 0; e < 16; ++e) {
        const int ix = ixs[e];
        const int lane_t = (ix >> 2) & 63;
        const int bitpos = ((ix >> 8) << 2) | (ix & 3);
        if (lane == lane_t) mask |= (1u << bitpos);
    }
    #pragma unroll
    for (int j = 0; j < 8; ++j) {
        float4 vv;
        vv.x = (mask >> (j * 4 + 0)) & 1u ? 1.f : 0.f;
        vv.y = (mask >> (j * 4 + 1)) & 1u ? 1.f : 0.f;
        vv.z = (mask >> (j * 4 + 2)) & 1u ? 1.f : 0.f;
        vv.w = (mask >> (j * 4 + 3)) & 1u ? 1.f : 0.f;
        *(float4*)(srowp + j * 256 + lane * 4) = vv;
    }

    const float* srow = S + (size_t)g * F;
    const float* rb = Rv + (size_t)bz * N * F;
    float4 vs = {0.f, 0.f, 0.f, 0.f};
    if (lane < 32) vs = *(const float4*)(srow + lane * 4);
    #pragma unroll
    for (int e = 0; e < 16; ++e) {
        float4 vv = vs;
        if (lane >= 32)
            vv = *(const float4*)(rb + (size_t)ixs[e] * F + (lane - 32) * 4);
        *(float4*)(edges_out + ((size_t)g * K_NE + rank[e]) * 256 + lane * 4) = vv;
    }
}

extern "C" void kernel_launch(void* const* d_in, const int* in_sizes, int n_in,
                              void* d_out, int out_size, void* d_ws, size_t ws_size,
                              hipStream_t stream) {
    (void)in_sizes; (void)n_in; (void)out_size; (void)ws_size;
    const float* recv = (const float*)d_in[0];
    const float* send = (const float*)d_in[1];
    float* out = (float*)d_out;
    float* sender_mat = out + EDGE_FLOATS;       // score scratch, then conn matrix
    float* x2 = (float*)((char*)d_ws + (262144u * 4));
    float* y2 = x2 + NSEND;

    // f16 hi/lo staging lives in the edges region (dead until topk_fused).
    _Float16* SH = (_Float16*)out;
    _Float16* SL = SH + NSEND * F;
    _Float16* RH = SL + NSEND * F;
    _Float16* RL = RH + NSEND * F;               // total 16.8 MB << 256 MB

    norms_kernel<<<4096, 256, 0, stream>>>(send, x2);
    norms_kernel<<<4096, 256, 0, stream>>>(recv, y2);
    convert_kernel<<<4096, 256, 0, stream>>>(send, recv, SH, SL, RH, RL);
    dim3 g1(16, 16, 8);
    score_mfma_kernel<<<g1, 256, 0, stream>>>(SH, SL, RH, RL, x2, y2, sender_mat);
    topk_fused_kernel<<<4096, 256, 0, stream>>>(send, recv, sender_mat, out);
}

// Round 17
// 161.600 us; speedup vs baseline: 2.4179x; 1.0651x over previous
//
#include <hip/hip_runtime.h>
#include <cstdint>

#define K_NE 16
constexpr int B = 8, N = 2048, F = 128;
constexpr size_t NSEND = (size_t)B * N;                 // 16384 sender rows
constexpr size_t EDGE_FLOATS = NSEND * K_NE * 256;      // 67,108,864
constexpr size_t SEND_FLOATS = (size_t)B * N * N;       // 33,554,432

typedef _Float16 half8 __attribute__((ext_vector_type(8)));
typedef _Float16 half4 __attribute__((ext_vector_type(4)));
typedef float floatx4 __attribute__((ext_vector_type(4)));

#define SCALE 2048.0f                    // exact power of 2
#define INV_SC2 2.384185791015625e-07f   // 2^-22, exact
#define F16_MIN_NORM 6.103515625e-05f    // 2^-14

// ---------------- K0: row norms (one wave per 128-float row) ----------------
__global__ __launch_bounds__(256) void norms_kernel(const float* __restrict__ X,
                                                    float* __restrict__ out) {
    int tid = blockIdx.x * 256 + threadIdx.x;
    int w = tid >> 6, lane = tid & 63;
    const float2 v = ((const float2*)(X + (size_t)w * F))[lane];
    float s = v.x * v.x + v.y * v.y;
    #pragma unroll
    for (int off = 32; off; off >>= 1) s += __shfl_xor(s, off);
    if (lane == 0) out[w] = s;
}

// ---------------- K0b: f32 -> scaled (f16 hi, f16 lo), denormal-free --------
__global__ __launch_bounds__(256) void convert_kernel(const float* __restrict__ S,
                                                      const float* __restrict__ Rv,
                                                      _Float16* __restrict__ SH,
                                                      _Float16* __restrict__ SL,
                                                      _Float16* __restrict__ RH,
                                                      _Float16* __restrict__ RL) {
    const int i = blockIdx.x * 256 + threadIdx.x;   // quad index
    const int half_n = (int)(NSEND * F / 4);        // 524288 quads per matrix
    const float* X; _Float16 *H, *L; int q;
    if (i < half_n) { X = S;  H = SH; L = SL; q = i; }
    else            { X = Rv; H = RH; L = RL; q = i - half_n; }
    const float4 v = ((const float4*)X)[q];
    float a[4] = {v.x * SCALE, v.y * SCALE, v.z * SCALE, v.w * SCALE};
    half4 h, l;
    #pragma unroll
    for (int c = 0; c < 4; ++c) {
        _Float16 hh = (_Float16)a[c];
        if (fabsf((float)hh) < F16_MIN_NORM) hh = (_Float16)0.0f;
        float lf = a[c] - (float)hh;
        _Float16 ll = (_Float16)lf;
        if (fabsf((float)ll) < F16_MIN_NORM) ll = (_Float16)0.0f;
        ((_Float16*)&h)[c] = hh;
        ((_Float16*)&l)[c] = ll;
    }
    *(half4*)(H + 4 * (size_t)q) = h;
    *(half4*)(L + 4 * (size_t)q) = l;
}

// ---------------- K1: MFMA score matrix, LDS-staged dbuf, 8 waves -----------
// v8: 128x128 block tile, 512 threads = 8 waves of 64x32 (acc[4][2]) ->
// 2 blocks/CU x 8 waves = 4 waves/SIMD (was 2). Same 64 KB dbuf LDS layout
// [buf][hi/lo][kg][row][8] as r16; per-(row,col) MFMA chain identical
// (same K-partition, ah*bh -> ah*bl -> al*bh) -> bit-identical scores.
__global__ __launch_bounds__(512) void score_mfma_kernel(
        const _Float16* __restrict__ SH, const _Float16* __restrict__ SL,
        const _Float16* __restrict__ RH, const _Float16* __restrict__ RL,
        const float* __restrict__ x2, const float* __restrict__ y2,
        float* __restrict__ scores) {
    __shared__ __attribute__((aligned(16))) _Float16 lA[2][2][4][128][8]; // 32 KB
    __shared__ __attribute__((aligned(16))) _Float16 lB[2][2][4][128][8]; // 32 KB
    const int bx = blockIdx.x, by = blockIdx.y, bz = blockIdx.z;
    const int t = threadIdx.x, lane = t & 63, wv = t >> 6;   // wv 0..7
    const int wrow0 = (wv >> 2) * 64;      // 0 or 64
    const int wcol0 = (wv & 3) * 32;       // 0,32,64,96
    const int lr = lane & 15, kg = lane >> 4;

    // staging slots: s = t + i*512 (i=0..1) covers 2(h)*4(kg)*128(row);
    // kg fastest -> 4 consecutive lanes read 64B contiguous global (coalesced)
    int s_h[2], s_kg[2], s_row[2];
    #pragma unroll
    for (int i = 0; i < 2; ++i) {
        const int s = t + (i << 9);
        s_h[i]   = s >> 9;
        s_row[i] = (s & 511) >> 2;
        s_kg[i]  = s & 3;
    }
    const size_t baseA = (size_t)(bz * N + by * 128);
    const size_t baseB = (size_t)(bz * N + bx * 128);

    // prologue: chunk 0 -> buf 0
    #pragma unroll
    for (int i = 0; i < 2; ++i) {
        const _Float16* sa = (s_h[i] ? SL : SH) + (baseA + s_row[i]) * F + s_kg[i] * 8;
        const _Float16* sb = (s_h[i] ? RL : RH) + (baseB + s_row[i]) * F + s_kg[i] * 8;
        *(half8*)&lA[0][s_h[i]][s_kg[i]][s_row[i]][0] = *(const half8*)sa;
        *(half8*)&lB[0][s_h[i]][s_kg[i]][s_row[i]][0] = *(const half8*)sb;
    }
    __syncthreads();

    floatx4 acc[4][2] = {};

    #pragma unroll
    for (int kc = 0; kc < 4; ++kc) {    // 4 chunks of BK=32 (k = kc*32 + kg*8 + j)
        const int cur = kc & 1;
        half8 pa[2], pb[2];
        if (kc < 3) {                   // prefetch next chunk (in flight during MFMA)
            const int ko = (kc + 1) * 32;
            #pragma unroll
            for (int i = 0; i < 2; ++i) {
                pa[i] = *(const half8*)((s_h[i] ? SL : SH) + (baseA + s_row[i]) * F + ko + s_kg[i] * 8);
                pb[i] = *(const half8*)((s_h[i] ? RL : RH) + (baseB + s_row[i]) * F + ko + s_kg[i] * 8);
            }
        }
        half8 ah[4], al[4];
        #pragma unroll
        for (int i = 0; i < 4; ++i) {
            ah[i] = *(const half8*)&lA[cur][0][kg][wrow0 + i * 16 + lr][0];
            al[i] = *(const half8*)&lA[cur][1][kg][wrow0 + i * 16 + lr][0];
        }
        #pragma unroll
        for (int j = 0; j < 2; ++j) {
            const half8 bh = *(const half8*)&lB[cur][0][kg][wcol0 + j * 16 + lr][0];
            const half8 bl = *(const half8*)&lB[cur][1][kg][wcol0 + j * 16 + lr][0];
            #pragma unroll
            for (int i = 0; i < 4; ++i) {
                acc[i][j] = __builtin_amdgcn_mfma_f32_16x16x32_f16(ah[i], bh, acc[i][j], 0, 0, 0);
                acc[i][j] = __builtin_amdgcn_mfma_f32_16x16x32_f16(ah[i], bl, acc[i][j], 0, 0, 0);
                acc[i][j] = __builtin_amdgcn_mfma_f32_16x16x32_f16(al[i], bh, acc[i][j], 0, 0, 0);
            }
        }
        if (kc < 3) {
            const int nxt = cur ^ 1;    // write other buffer; one barrier/chunk
            #pragma unroll
            for (int i = 0; i < 2; ++i) {
                *(half8*)&lA[nxt][s_h[i]][s_kg[i]][s_row[i]][0] = pa[i];
                *(half8*)&lB[nxt][s_h[i]][s_kg[i]][s_row[i]][0] = pb[i];
            }
            __syncthreads();
        }
    }

    float* outb = scores + (size_t)bz * N * N;
    const float* x2b = x2 + (size_t)bz * N;
    const float* y2b = y2 + (size_t)bz * N;
    #pragma unroll
    for (int j = 0; j < 2; ++j) {
        const int col = bx * 128 + wcol0 + j * 16 + lr;
        const float yv = y2b[col];
        #pragma unroll
        for (int i = 0; i < 4; ++i) {
            #pragma unroll
            for (int r = 0; r < 4; ++r) {
                const int row = by * 128 + wrow0 + i * 16 + (lane >> 4) * 4 + r;
                const float d = acc[i][j][r] * INV_SC2;   // exact unscale
                outb[(size_t)row * N + col] = fabsf((-2.0f * d + x2b[row]) + yv);
            }
        }
    }
}

// ------- K2: fused top-16 via threshold filter + bitonic select (r14) -------
__global__ __launch_bounds__(256) void topk_fused_kernel(const float* __restrict__ S,
                                                         const float* __restrict__ Rv,
                                                         float* __restrict__ scores,
                                                         float* __restrict__ edges_out) {
    __shared__ uint32_t rowbuf[4][N];     // 32 KB, lane-private slices
    __shared__ double candbuf[4][64];     // 2 KB candidate buffers
    const int t = threadIdx.x;
    const int lane = t & 63;
    const int w = t >> 6;
    const int g = blockIdx.x * 4 + w;     // global sender id 0..16383
    const int bz = g >> 11;               // batch
    uint32_t* lds = rowbuf[w];
    double* cbuf = candbuf[w];
    float* srowp = scores + (size_t)g * N;
    const uint4* sr = (const uint4*)srowp;
    const double MAGIC = 4503599627370496.0;   // 2^52

    uint32_t mk = 0xFFFFFFFFu;
    #pragma unroll
    for (int jj = 0; jj < 8; ++jj) {
        uint4 u = sr[jj * 64 + lane];
        *(uint4*)(&lds[jj * 256 + lane * 4]) = u;
        mk = mk < u.x ? mk : u.x;
        mk = mk < u.y ? mk : u.y;
        mk = mk < u.z ? mk : u.z;
        mk = mk < u.w ? mk : u.w;
    }

    uint32_t v = mk;
    #pragma unroll
    for (int k = 2; k <= 64; k <<= 1) {
        #pragma unroll
        for (int j = k >> 1; j >= 1; j >>= 1) {
            uint32_t o = (uint32_t)__shfl_xor((int)v, j);
            const bool take_min = (((lane & j) == 0) == ((lane & k) == 0));
            const uint32_t mn = v < o ? v : o;
            const uint32_t mx = v < o ? o : v;
            v = take_min ? mn : mx;
        }
    }
    const uint32_t T16 = (uint32_t)__shfl((int)v, 15);

    int cnt = 0;
    #pragma unroll
    for (int jj = 0; jj < 8; ++jj) {
        const uint4 u = *(const uint4*)(&lds[jj * 256 + lane * 4]);
        #pragma unroll
        for (int c = 0; c < 4; ++c) {
            const uint32_t key = (c == 0) ? u.x : (c == 1) ? u.y : (c == 2) ? u.z : u.w;
            const bool f = key <= T16;
            const unsigned long long m = __ballot(f);
            if (f) {
                const int pos = cnt + __popcll(m & ((1ull << lane) - 1ull));
                if (pos < 64)
                    cbuf[pos] = (double)key * 2048.0 + (double)(jj * 256 + lane * 4 + c);
            }
            cnt += __popcll(m);
        }
    }

    int ixs[16];
    if (cnt <= 64) {
        double d = (lane < cnt) ? cbuf[lane] : 1e300;
        #pragma unroll
        for (int k = 2; k <= 64; k <<= 1) {
            #pragma unroll
            for (int j = k >> 1; j >= 1; j >>= 1) {
                const double o = __shfl_xor(d, j);
                const bool take_min = (((lane & j) == 0) == ((lane & k) == 0));
                d = take_min ? fmin(d, o) : fmax(d, o);
            }
        }
        const int myidx = (int)(__double_as_longlong(d + MAGIC) & 2047);
        #pragma unroll
        for (int e = 0; e < 16; ++e) ixs[e] = __shfl(myidx, e);
    } else {
        uint32_t fk = 0xFFFFFFFFu, fi = 0;
        #pragma unroll
        for (int jj = 0; jj < 8; ++jj) {
            const uint4 u = *(const uint4*)(&lds[jj * 256 + lane * 4]);
            const uint32_t base = (uint32_t)(jj * 256 + lane * 4);
            if (u.x < fk) { fk = u.x; fi = base; }
            if (u.y < fk) { fk = u.y; fi = base + 1; }
            if (u.z < fk) { fk = u.z; fi = base + 2; }
            if (u.w < fk) { fk = u.w; fi = base + 3; }
        }
        #pragma unroll
        for (int it = 0; it < 16; ++it) {
            const uint32_t ck = fk, ci = fi;
            uint32_t gk = fk, gi = fi;
            #pragma unroll
            for (int off = 32; off; off >>= 1) {
                uint32_t ok = (uint32_t)__shfl_xor((int)gk, off);
                uint32_t oi = (uint32_t)__shfl_xor((int)gi, off);
                if (ok < gk || (ok == gk && oi < gi)) { gk = ok; gi = oi; }
            }
            ixs[it] = (int)gi;
            if (ck == gk && ci == gi) {
                lds[gi] = 0xFFFFFFFFu;
                fk = 0xFFFFFFFFu; fi = 0;
                #pragma unroll
                for (int jj = 0; jj < 8; ++jj) {
                    const uint4 u = *(const uint4*)(&lds[jj * 256 + lane * 4]);
                    const uint32_t base = (uint32_t)(jj * 256 + lane * 4);
                    if (u.x < fk) { fk = u.x; fi = base; }
                    if (u.y < fk) { fk = u.y; fi = base + 1; }
                    if (u.z < fk) { fk = u.z; fi = base + 2; }
                    if (u.w < fk) { fk = u.w; fi = base + 3; }
                }
            }
        }
    }

    int rank[16];
    #pragma unroll
    for (int e = 0; e < 16; ++e) {
        int r = 0;
        #pragma unroll
        for (int f = 0; f < 16; ++f) r += (ixs[f] < ixs[e]) ? 1 : 0;
        rank[e] = r;
    }

    uint32_t mask = 0;
    #pragma unroll
    for (int e = 0; e < 16; ++e) {
        const int ix = ixs[e];
        const int lane_t = (ix >> 2) & 63;
        const int bitpos = ((ix >> 8) << 2) | (ix & 3);
        if (lane == lane_t) mask |= (1u << bitpos);
    }
    #pragma unroll
    for (int j = 0; j < 8; ++j) {
        float4 vv;
        vv.x = (mask >> (j * 4 + 0)) & 1u ? 1.f : 0.f;
        vv.y = (mask >> (j * 4 + 1)) & 1u ? 1.f : 0.f;
        vv.z = (mask >> (j * 4 + 2)) & 1u ? 1.f : 0.f;
        vv.w = (mask >> (j * 4 + 3)) & 1u ? 1.f : 0.f;
        *(float4*)(srowp + j * 256 + lane * 4) = vv;
    }

    const float* srow = S + (size_t)g * F;
    const float* rb = Rv + (size_t)bz * N * F;
    float4 vs = {0.f, 0.f, 0.f, 0.f};
    if (lane < 32) vs = *(const float4*)(srow + lane * 4);
    #pragma unroll
    for (int e = 0; e < 16; ++e) {
        float4 vv = vs;
        if (lane >= 32)
            vv = *(const float4*)(rb + (size_t)ixs[e] * F + (lane - 32) * 4);
        *(float4*)(edges_out + ((size_t)g * K_NE + rank[e]) * 256 + lane * 4) = vv;
    }
}

extern "C" void kernel_launch(void* const* d_in, const int* in_sizes, int n_in,
                              void* d_out, int out_size, void* d_ws, size_t ws_size,
                              hipStream_t stream) {
    (void)in_sizes; (void)n_in; (void)out_size; (void)ws_size;
    const float* recv = (const float*)d_in[0];
    const float* send = (const float*)d_in[1];
    float* out = (float*)d_out;
    float* sender_mat = out + EDGE_FLOATS;       // score scratch, then conn matrix
    float* x2 = (float*)((char*)d_ws + (262144u * 4));
    float* y2 = x2 + NSEND;

    // f16 hi/lo staging lives in the edges region (dead until topk_fused).
    _Float16* SH = (_Float16*)out;
    _Float16* SL = SH + NSEND * F;
    _Float16* RH = SL + NSEND * F;
    _Float16* RL = RH + NSEND * F;               // total 16.8 MB << 256 MB

    norms_kernel<<<4096, 256, 0, stream>>>(send, x2);
    norms_kernel<<<4096, 256, 0, stream>>>(recv, y2);
    convert_kernel<<<4096, 256, 0, stream>>>(send, recv, SH, SL, RH, RL);
    dim3 g1(16, 16, 8);
    score_mfma_kernel<<<g1, 512, 0, stream>>>(SH, SL, RH, RL, x2, y2, sender_mat);
    topk_fused_kernel<<<4096, 256, 0, stream>>>(send, recv, sender_mat, out);
}

// Round 18
// 157.978 us; speedup vs baseline: 2.4733x; 1.0229x over previous
//
#include <hip/hip_runtime.h>
#include <cstdint>

#define K_NE 16
constexpr int B = 8, N = 2048, F = 128;
constexpr size_t NSEND = (size_t)B * N;                 // 16384 sender rows
constexpr size_t EDGE_FLOATS = NSEND * K_NE * 256;      // 67,108,864
constexpr size_t SEND_FLOATS = (size_t)B * N * N;       // 33,554,432

typedef _Float16 half8 __attribute__((ext_vector_type(8)));
typedef _Float16 half2v __attribute__((ext_vector_type(2)));
typedef float floatx4 __attribute__((ext_vector_type(4)));

#define SCALE 2048.0f                    // exact power of 2
#define INV_SC2 2.384185791015625e-07f   // 2^-22, exact
#define F16_MIN_NORM 6.103515625e-05f    // 2^-14

// ------------ K0: fused row norms + f32 -> scaled (f16 hi,lo) convert -------
// One wave per row (senders then receivers): 2 floats/lane. Norm via shfl
// reduce; per-element scaled hi/lo split identical to r16's convert (FTZ'd,
// denormal-free) -> bit-identical staging data.
__global__ __launch_bounds__(256) void prep_kernel(const float* __restrict__ S,
                                                   const float* __restrict__ Rv,
                                                   float* __restrict__ x2,
                                                   float* __restrict__ y2,
                                                   _Float16* __restrict__ SH,
                                                   _Float16* __restrict__ SL,
                                                   _Float16* __restrict__ RH,
                                                   _Float16* __restrict__ RL) {
    const int tid = blockIdx.x * 256 + threadIdx.x;
    const int w = tid >> 6, lane = tid & 63;           // w = 0..32767
    const bool isR = w >= (int)NSEND;
    const int row = isR ? w - (int)NSEND : w;
    const float* X = isR ? Rv : S;
    _Float16* H = isR ? RH : SH;
    _Float16* L = isR ? RL : SL;
    float* nrm = isR ? y2 : x2;

    const float2 v = ((const float2*)(X + (size_t)row * F))[lane];
    float s = v.x * v.x + v.y * v.y;
    #pragma unroll
    for (int off = 32; off; off >>= 1) s += __shfl_xor(s, off);
    if (lane == 0) nrm[row] = s;

    const float a0 = v.x * SCALE, a1 = v.y * SCALE;
    _Float16 h0 = (_Float16)a0;
    if (fabsf((float)h0) < F16_MIN_NORM) h0 = (_Float16)0.0f;
    _Float16 l0 = (_Float16)(a0 - (float)h0);
    if (fabsf((float)l0) < F16_MIN_NORM) l0 = (_Float16)0.0f;
    _Float16 h1 = (_Float16)a1;
    if (fabsf((float)h1) < F16_MIN_NORM) h1 = (_Float16)0.0f;
    _Float16 l1 = (_Float16)(a1 - (float)h1);
    if (fabsf((float)l1) < F16_MIN_NORM) l1 = (_Float16)0.0f;
    half2v hv = {h0, h1}, lv = {l0, l1};
    *(half2v*)(H + (size_t)row * F + lane * 2) = hv;
    *(half2v*)(L + (size_t)row * F + lane * 2) = lv;
}

// ---------------- K1: MFMA score matrix (frozen r17) ------------------------
// 128x128 block tile, 512 threads = 8 waves of 64x32 (acc[4][2]);
// BK=32 chunks in 64 KB dbuf LDS [buf][hi/lo][kg][row][8]; bit-identical
// scores to r13/r16/r17 (same K-partition, ah*bh -> ah*bl -> al*bh).
__global__ __launch_bounds__(512) void score_mfma_kernel(
        const _Float16* __restrict__ SH, const _Float16* __restrict__ SL,
        const _Float16* __restrict__ RH, const _Float16* __restrict__ RL,
        const float* __restrict__ x2, const float* __restrict__ y2,
        float* __restrict__ scores) {
    __shared__ __attribute__((aligned(16))) _Float16 lA[2][2][4][128][8]; // 32 KB
    __shared__ __attribute__((aligned(16))) _Float16 lB[2][2][4][128][8]; // 32 KB
    const int bx = blockIdx.x, by = blockIdx.y, bz = blockIdx.z;
    const int t = threadIdx.x, lane = t & 63, wv = t >> 6;   // wv 0..7
    const int wrow0 = (wv >> 2) * 64;      // 0 or 64
    const int wcol0 = (wv & 3) * 32;       // 0,32,64,96
    const int lr = lane & 15, kg = lane >> 4;

    int s_h[2], s_kg[2], s_row[2];
    #pragma unroll
    for (int i = 0; i < 2; ++i) {
        const int s = t + (i << 9);
        s_h[i]   = s >> 9;
        s_row[i] = (s & 511) >> 2;
        s_kg[i]  = s & 3;
    }
    const size_t baseA = (size_t)(bz * N + by * 128);
    const size_t baseB = (size_t)(bz * N + bx * 128);

    #pragma unroll
    for (int i = 0; i < 2; ++i) {
        const _Float16* sa = (s_h[i] ? SL : SH) + (baseA + s_row[i]) * F + s_kg[i] * 8;
        const _Float16* sb = (s_h[i] ? RL : RH) + (baseB + s_row[i]) * F + s_kg[i] * 8;
        *(half8*)&lA[0][s_h[i]][s_kg[i]][s_row[i]][0] = *(const half8*)sa;
        *(half8*)&lB[0][s_h[i]][s_kg[i]][s_row[i]][0] = *(const half8*)sb;
    }
    __syncthreads();

    floatx4 acc[4][2] = {};

    #pragma unroll
    for (int kc = 0; kc < 4; ++kc) {    // 4 chunks of BK=32
        const int cur = kc & 1;
        half8 pa[2], pb[2];
        if (kc < 3) {
            const int ko = (kc + 1) * 32;
            #pragma unroll
            for (int i = 0; i < 2; ++i) {
                pa[i] = *(const half8*)((s_h[i] ? SL : SH) + (baseA + s_row[i]) * F + ko + s_kg[i] * 8);
                pb[i] = *(const half8*)((s_h[i] ? RL : RH) + (baseB + s_row[i]) * F + ko + s_kg[i] * 8);
            }
        }
        half8 ah[4], al[4];
        #pragma unroll
        for (int i = 0; i < 4; ++i) {
            ah[i] = *(const half8*)&lA[cur][0][kg][wrow0 + i * 16 + lr][0];
            al[i] = *(const half8*)&lA[cur][1][kg][wrow0 + i * 16 + lr][0];
        }
        #pragma unroll
        for (int j = 0; j < 2; ++j) {
            const half8 bh = *(const half8*)&lB[cur][0][kg][wcol0 + j * 16 + lr][0];
            const half8 bl = *(const half8*)&lB[cur][1][kg][wcol0 + j * 16 + lr][0];
            #pragma unroll
            for (int i = 0; i < 4; ++i) {
                acc[i][j] = __builtin_amdgcn_mfma_f32_16x16x32_f16(ah[i], bh, acc[i][j], 0, 0, 0);
                acc[i][j] = __builtin_amdgcn_mfma_f32_16x16x32_f16(ah[i], bl, acc[i][j], 0, 0, 0);
                acc[i][j] = __builtin_amdgcn_mfma_f32_16x16x32_f16(al[i], bh, acc[i][j], 0, 0, 0);
            }
        }
        if (kc < 3) {
            const int nxt = cur ^ 1;
            #pragma unroll
            for (int i = 0; i < 2; ++i) {
                *(half8*)&lA[nxt][s_h[i]][s_kg[i]][s_row[i]][0] = pa[i];
                *(half8*)&lB[nxt][s_h[i]][s_kg[i]][s_row[i]][0] = pb[i];
            }
            __syncthreads();
        }
    }

    float* outb = scores + (size_t)bz * N * N;
    const float* x2b = x2 + (size_t)bz * N;
    const float* y2b = y2 + (size_t)bz * N;
    #pragma unroll
    for (int j = 0; j < 2; ++j) {
        const int col = bx * 128 + wcol0 + j * 16 + lr;
        const float yv = y2b[col];
        #pragma unroll
        for (int i = 0; i < 4; ++i) {
            #pragma unroll
            for (int r = 0; r < 4; ++r) {
                const int row = by * 128 + wrow0 + i * 16 + (lane >> 4) * 4 + r;
                const float d = acc[i][j][r] * INV_SC2;   // exact unscale
                outb[(size_t)row * N + col] = fabsf((-2.0f * d + x2b[row]) + yv);
            }
        }
    }
}

#define KEYC(U, C) ((C) == 0 ? (U).x : (C) == 1 ? (U).y : (C) == 2 ? (U).z : (U).w)

// ------- K2: fused top-16, fully register-resident row (no rowbuf LDS) ------
// Row kept in 8x uint4 registers. T16 = 16th-smallest lane-min (bitonic of
// lane-mins); candidates (key <= T16) counted per lane, placed in cbuf via
// shfl_up prefix offsets (order irrelevant: the f64 bitonic sorts), top-16 =
// lanes 0..15 of the sort. Fallback (cnt>64): register-masked iterative
// lexicographic extraction (exact). LDS = 2 KB -> 8 blocks/CU (was 4).
__global__ __launch_bounds__(256) void topk_fused_kernel(const float* __restrict__ S,
                                                         const float* __restrict__ Rv,
                                                         float* __restrict__ scores,
                                                         float* __restrict__ edges_out) {
    __shared__ double candbuf[4][64];     // 2 KB candidate buffers
    const int t = threadIdx.x;
    const int lane = t & 63;
    const int w = t >> 6;
    const int g = blockIdx.x * 4 + w;     // global sender id 0..16383
    const int bz = g >> 11;               // batch
    double* cbuf = candbuf[w];
    float* srowp = scores + (size_t)g * N;
    const uint4* sr = (const uint4*)srowp;
    const double MAGIC = 4503599627370496.0;   // 2^52

    // ---- load row into registers; per-lane value-min ----------------------
    uint4 u[8];
    uint32_t mk = 0xFFFFFFFFu;
    #pragma unroll
    for (int jj = 0; jj < 8; ++jj) {
        u[jj] = sr[jj * 64 + lane];
        mk = mk < u[jj].x ? mk : u[jj].x;
        mk = mk < u[jj].y ? mk : u[jj].y;
        mk = mk < u[jj].z ? mk : u[jj].z;
        mk = mk < u[jj].w ? mk : u[jj].w;
    }

    // ---- bitonic sort of lane-mins (ascending) -> T16 = sorted[15] --------
    uint32_t v = mk;
    #pragma unroll
    for (int k = 2; k <= 64; k <<= 1) {
        #pragma unroll
        for (int j = k >> 1; j >= 1; j >>= 1) {
            uint32_t o = (uint32_t)__shfl_xor((int)v, j);
            const bool take_min = (((lane & j) == 0) == ((lane & k) == 0));
            const uint32_t mn = v < o ? v : o;
            const uint32_t mx = v < o ? o : v;
            v = take_min ? mn : mx;
        }
    }
    const uint32_t T16 = (uint32_t)__shfl((int)v, 15);

    // ---- per-lane candidate count + prefix-sum offsets --------------------
    int myc = 0;
    #pragma unroll
    for (int jj = 0; jj < 8; ++jj)
        #pragma unroll
        for (int c = 0; c < 4; ++c)
            myc += (KEYC(u[jj], c) <= T16) ? 1 : 0;
    int off = myc;
    #pragma unroll
    for (int d = 1; d < 64; d <<= 1) {
        const int o = __shfl_up(off, d);
        if (lane >= d) off += o;
    }
    const int total = __shfl(off, 63);
    const int base = off - myc;

    int ixs[16];
    if (total <= 64) {
        // ---- write my candidates at my offsets; f64 bitonic; top-16 ------
        int p = base;
        #pragma unroll
        for (int jj = 0; jj < 8; ++jj)
            #pragma unroll
            for (int c = 0; c < 4; ++c) {
                const uint32_t key = KEYC(u[jj], c);
                if (key <= T16) {
                    cbuf[p] = (double)key * 2048.0 + (double)(jj * 256 + lane * 4 + c);
                    ++p;
                }
            }
        double d = (lane < total) ? cbuf[lane] : 1e300;
        #pragma unroll
        for (int k = 2; k <= 64; k <<= 1) {
            #pragma unroll
            for (int j = k >> 1; j >= 1; j >>= 1) {
                const double o = __shfl_xor(d, j);
                const bool take_min = (((lane & j) == 0) == ((lane & k) == 0));
                d = take_min ? fmin(d, o) : fmax(d, o);
            }
        }
        const int myidx = (int)(__double_as_longlong(d + MAGIC) & 2047);
        #pragma unroll
        for (int e = 0; e < 16; ++e) ixs[e] = __shfl(myidx, e);
    } else {
        // ---- fallback (tie storm): register-masked iterative extraction --
        uint32_t fk = 0xFFFFFFFFu, fi = 0;
        #pragma unroll
        for (int jj = 0; jj < 8; ++jj) {
            const uint32_t bse = (uint32_t)(jj * 256 + lane * 4);
            if (u[jj].x < fk) { fk = u[jj].x; fi = bse; }
            if (u[jj].y < fk) { fk = u[jj].y; fi = bse + 1; }
            if (u[jj].z < fk) { fk = u[jj].z; fi = bse + 2; }
            if (u[jj].w < fk) { fk = u[jj].w; fi = bse + 3; }
        }
        #pragma unroll
        for (int it = 0; it < 16; ++it) {
            const uint32_t ck = fk, ci = fi;
            uint32_t gk = fk, gi = fi;
            #pragma unroll
            for (int o2 = 32; o2; o2 >>= 1) {
                uint32_t ok = (uint32_t)__shfl_xor((int)gk, o2);
                uint32_t oi = (uint32_t)__shfl_xor((int)gi, o2);
                if (ok < gk || (ok == gk && oi < gi)) { gk = ok; gi = oi; }
            }
            ixs[it] = (int)gi;
            if (ck == gk && ci == gi) {       // owner deletes own register
                const int djj = (int)(gi >> 8), dc = (int)(gi & 3);
                #pragma unroll
                for (int jj = 0; jj < 8; ++jj)
                    if (jj == djj) {
                        if (dc == 0) u[jj].x = 0xFFFFFFFFu;
                        else if (dc == 1) u[jj].y = 0xFFFFFFFFu;
                        else if (dc == 2) u[jj].z = 0xFFFFFFFFu;
                        else u[jj].w = 0xFFFFFFFFu;
                    }
                fk = 0xFFFFFFFFu; fi = 0;
                #pragma unroll
                for (int jj = 0; jj < 8; ++jj) {
                    const uint32_t bse = (uint32_t)(jj * 256 + lane * 4);
                    if (u[jj].x < fk) { fk = u[jj].x; fi = bse; }
                    if (u[jj].y < fk) { fk = u[jj].y; fi = bse + 1; }
                    if (u[jj].z < fk) { fk = u[jj].z; fi = bse + 2; }
                    if (u[jj].w < fk) { fk = u[jj].w; fi = bse + 3; }
                }
            }
        }
    }

    // ---- ranks: output slot = ascending receiver-index position -----------
    int rank[16];
    #pragma unroll
    for (int e = 0; e < 16; ++e) {
        int r = 0;
        #pragma unroll
        for (int f = 0; f < 16; ++f) r += (ixs[f] < ixs[e]) ? 1 : 0;
        rank[e] = r;
    }

    // ---- connectivity row (overwrites this wave's score row) --------------
    uint32_t mask = 0;
    #pragma unroll
    for (int e = 0; e < 16; ++e) {
        const int ix = ixs[e];
        const int lane_t = (ix >> 2) & 63;
        const int bitpos = ((ix >> 8) << 2) | (ix & 3);
        if (lane == lane_t) mask |= (1u << bitpos);
    }
    #pragma unroll
    for (int j = 0; j < 8; ++j) {
        float4 vv;
        vv.x = (mask >> (j * 4 + 0)) & 1u ? 1.f : 0.f;
        vv.y = (mask >> (j * 4 + 1)) & 1u ? 1.f : 0.f;
        vv.z = (mask >> (j * 4 + 2)) & 1u ? 1.f : 0.f;
        vv.w = (mask >> (j * 4 + 3)) & 1u ? 1.f : 0.f;
        *(float4*)(srowp + j * 256 + lane * 4) = vv;
    }

    // ---- edge rows: [sender_feat(128) | recv_feat(128)] -------------------
    const float* srow = S + (size_t)g * F;
    const float* rb = Rv + (size_t)bz * N * F;
    float4 vs = {0.f, 0.f, 0.f, 0.f};
    if (lane < 32) vs = *(const float4*)(srow + lane * 4);
    #pragma unroll
    for (int e = 0; e < 16; ++e) {
        float4 vv = vs;
        if (lane >= 32)
            vv = *(const float4*)(rb + (size_t)ixs[e] * F + (lane - 32) * 4);
        *(float4*)(edges_out + ((size_t)g * K_NE + rank[e]) * 256 + lane * 4) = vv;
    }
}

extern "C" void kernel_launch(void* const* d_in, const int* in_sizes, int n_in,
                              void* d_out, int out_size, void* d_ws, size_t ws_size,
                              hipStream_t stream) {
    (void)in_sizes; (void)n_in; (void)out_size; (void)ws_size;
    const float* recv = (const float*)d_in[0];
    const float* send = (const float*)d_in[1];
    float* out = (float*)d_out;
    float* sender_mat = out + EDGE_FLOATS;       // score scratch, then conn matrix
    float* x2 = (float*)((char*)d_ws + (262144u * 4));
    float* y2 = x2 + NSEND;

    // f16 hi/lo staging lives in the edges region (dead until topk_fused).
    _Float16* SH = (_Float16*)out;
    _Float16* SL = SH + NSEND * F;
    _Float16* RH = SL + NSEND * F;
    _Float16* RL = RH + NSEND * F;               // total 16.8 MB << 256 MB

    prep_kernel<<<8192, 256, 0, stream>>>(send, recv, x2, y2, SH, SL, RH, RL);
    dim3 g1(16, 16, 8);
    score_mfma_kernel<<<g1, 512, 0, stream>>>(SH, SL, RH, RL, x2, y2, sender_mat);
    topk_fused_kernel<<<4096, 256, 0, stream>>>(send, recv, sender_mat, out);
}